// Round 1
// baseline (236.711 us; speedup 1.0000x reference)
//
#include <hip/hip_runtime.h>
#include <math.h>

// Problem constants
#define Bsz 32
#define Nn  4096
#define DU  64
#define Dm  128
#define ZSTR 132   // padded LDS row stride (floats); 132*4=528B, 16B aligned

// workspace layout (float offsets)
#define WS_WKQ 0      // [2][128]  Wk-slice @ q  per head
#define WS_BKQ 256    // [2]       bk-slice . q
#define WS_A   288    // [32][2]   sum of alpha
#define WS_S   384    // [32][2][128] sum alpha*z

__device__ __forceinline__ float gelu_tanh(float x) {
    const float c0 = 0.7978845608028654f;
    const float c1 = 0.044715f;
    float y = c0 * (x + c1 * x * x * x);
    float t = __expf(-2.0f * fabsf(y));      // in (0,1], no overflow
    float th = (1.0f - t) / (1.0f + t);      // |tanh(y)|
    th = copysignf(th, y);
    return 0.5f * x * (1.0f + th);
}

__device__ __forceinline__ void fma4(float4& acc, float s, const float4& w) {
    acc.x += s * w.x; acc.y += s * w.y; acc.z += s * w.z; acc.w += s * w.w;
}

// K0: precompute wkq/bkq, zero S/A accumulators. 1 block x 256.
__global__ __launch_bounds__(256) void precompute_kernel(
    const float* __restrict__ embed, const float* __restrict__ Wq,
    const float* __restrict__ bq, const float* __restrict__ Wk,
    const float* __restrict__ bk, float* __restrict__ ws)
{
    __shared__ float qv[128];
    const int tid = threadIdx.x;

    for (int idx = tid; idx < 64;   idx += 256) ws[WS_A + idx] = 0.f;
    for (int idx = tid; idx < 8192; idx += 256) ws[WS_S + idx] = 0.f;

    if (tid < 128) {
        float s = bq[tid];
        for (int j = 0; j < 128; ++j) s += embed[j] * Wq[j * 128 + tid];
        qv[tid] = s;
    }
    __syncthreads();
    if (tid < 128) {
        float s0 = 0.f, s1 = 0.f;
        for (int dh = 0; dh < 64; ++dh) {
            s0 += Wk[tid * 128 + dh]      * qv[dh];
            s1 += Wk[tid * 128 + 64 + dh] * qv[64 + dh];
        }
        ws[WS_WKQ + tid]       = s0;
        ws[WS_WKQ + 128 + tid] = s1;
    }
    if (tid < 2) {
        float s = 0.f;
        for (int dh = 0; dh < 64; ++dh) s += bk[tid * 64 + dh] * qv[tid * 64 + dh];
        ws[WS_BKQ + tid] = s;
    }
}

// K1: fused MLP + alpha + S/A accumulation. One block = 32 rows of one batch.
__global__ __launch_bounds__(256) void mlp_pool_kernel(
    const float* __restrict__ u,  const float* __restrict__ W1,
    const float* __restrict__ b1, const float* __restrict__ W2,
    const float* __restrict__ b2, float* __restrict__ ws)
{
    __shared__ float h1s[32 * ZSTR];
    __shared__ float zs [32 * ZSTR];
    __shared__ float wkqs[256];
    __shared__ float bkqs[2];
    __shared__ float alphas[64];   // [r][h]

    const int tid = threadIdx.x;
    const int b   = blockIdx.x >> 7;           // / 128 tiles per batch
    const int n0  = (blockIdx.x & 127) << 5;   // * 32 rows

    wkqs[tid & 255] = ws[WS_WKQ + (tid & 255)];
    if (tid < 2) bkqs[tid] = ws[WS_BKQ + tid];

    const int rg = tid >> 5;      // 0..7
    const int cg = tid & 31;      // 0..31
    const int r0 = rg << 2;       // row base (4 rows)
    const int j0 = cg << 2;       // col base (4 cols)

    const float* ub = u + ((size_t)b * Nn + n0) * DU;

    // ---- phase 1: H1 = gelu(U @ W1 + b1), U: [32,64] global, H1 -> LDS
    {
        float4 acc0, acc1, acc2, acc3;
        float4 bv = *(const float4*)&b1[j0];
        acc0 = bv; acc1 = bv; acc2 = bv; acc3 = bv;
        for (int kk = 0; kk < 16; ++kk) {
            float4 a0 = *(const float4*)&ub[(r0 + 0) * DU + kk * 4];
            float4 a1 = *(const float4*)&ub[(r0 + 1) * DU + kk * 4];
            float4 a2 = *(const float4*)&ub[(r0 + 2) * DU + kk * 4];
            float4 a3 = *(const float4*)&ub[(r0 + 3) * DU + kk * 4];
            float4 w0 = *(const float4*)&W1[(kk * 4 + 0) * Dm + j0];
            float4 w1 = *(const float4*)&W1[(kk * 4 + 1) * Dm + j0];
            float4 w2 = *(const float4*)&W1[(kk * 4 + 2) * Dm + j0];
            float4 w3 = *(const float4*)&W1[(kk * 4 + 3) * Dm + j0];
            fma4(acc0, a0.x, w0); fma4(acc0, a0.y, w1); fma4(acc0, a0.z, w2); fma4(acc0, a0.w, w3);
            fma4(acc1, a1.x, w0); fma4(acc1, a1.y, w1); fma4(acc1, a1.z, w2); fma4(acc1, a1.w, w3);
            fma4(acc2, a2.x, w0); fma4(acc2, a2.y, w1); fma4(acc2, a2.z, w2); fma4(acc2, a2.w, w3);
            fma4(acc3, a3.x, w0); fma4(acc3, a3.y, w1); fma4(acc3, a3.z, w2); fma4(acc3, a3.w, w3);
        }
        float4 g;
        g.x = gelu_tanh(acc0.x); g.y = gelu_tanh(acc0.y); g.z = gelu_tanh(acc0.z); g.w = gelu_tanh(acc0.w);
        *(float4*)&h1s[(r0 + 0) * ZSTR + j0] = g;
        g.x = gelu_tanh(acc1.x); g.y = gelu_tanh(acc1.y); g.z = gelu_tanh(acc1.z); g.w = gelu_tanh(acc1.w);
        *(float4*)&h1s[(r0 + 1) * ZSTR + j0] = g;
        g.x = gelu_tanh(acc2.x); g.y = gelu_tanh(acc2.y); g.z = gelu_tanh(acc2.z); g.w = gelu_tanh(acc2.w);
        *(float4*)&h1s[(r0 + 2) * ZSTR + j0] = g;
        g.x = gelu_tanh(acc3.x); g.y = gelu_tanh(acc3.y); g.z = gelu_tanh(acc3.z); g.w = gelu_tanh(acc3.w);
        *(float4*)&h1s[(r0 + 3) * ZSTR + j0] = g;
    }
    __syncthreads();

    // ---- phase 2: Z = gelu(H1 @ W2 + b2), H1 from LDS (broadcast reads)
    {
        float4 acc0, acc1, acc2, acc3;
        float4 bv = *(const float4*)&b2[j0];
        acc0 = bv; acc1 = bv; acc2 = bv; acc3 = bv;
        for (int kk = 0; kk < 32; ++kk) {
            float4 a0 = *(const float4*)&h1s[(r0 + 0) * ZSTR + kk * 4];
            float4 a1 = *(const float4*)&h1s[(r0 + 1) * ZSTR + kk * 4];
            float4 a2 = *(const float4*)&h1s[(r0 + 2) * ZSTR + kk * 4];
            float4 a3 = *(const float4*)&h1s[(r0 + 3) * ZSTR + kk * 4];
            float4 w0 = *(const float4*)&W2[(kk * 4 + 0) * Dm + j0];
            float4 w1 = *(const float4*)&W2[(kk * 4 + 1) * Dm + j0];
            float4 w2 = *(const float4*)&W2[(kk * 4 + 2) * Dm + j0];
            float4 w3 = *(const float4*)&W2[(kk * 4 + 3) * Dm + j0];
            fma4(acc0, a0.x, w0); fma4(acc0, a0.y, w1); fma4(acc0, a0.z, w2); fma4(acc0, a0.w, w3);
            fma4(acc1, a1.x, w0); fma4(acc1, a1.y, w1); fma4(acc1, a1.z, w2); fma4(acc1, a1.w, w3);
            fma4(acc2, a2.x, w0); fma4(acc2, a2.y, w1); fma4(acc2, a2.z, w2); fma4(acc2, a2.w, w3);
            fma4(acc3, a3.x, w0); fma4(acc3, a3.y, w1); fma4(acc3, a3.z, w2); fma4(acc3, a3.w, w3);
        }
        float4 g;
        g.x = gelu_tanh(acc0.x); g.y = gelu_tanh(acc0.y); g.z = gelu_tanh(acc0.z); g.w = gelu_tanh(acc0.w);
        *(float4*)&zs[(r0 + 0) * ZSTR + j0] = g;
        g.x = gelu_tanh(acc1.x); g.y = gelu_tanh(acc1.y); g.z = gelu_tanh(acc1.z); g.w = gelu_tanh(acc1.w);
        *(float4*)&zs[(r0 + 1) * ZSTR + j0] = g;
        g.x = gelu_tanh(acc2.x); g.y = gelu_tanh(acc2.y); g.z = gelu_tanh(acc2.z); g.w = gelu_tanh(acc2.w);
        *(float4*)&zs[(r0 + 2) * ZSTR + j0] = g;
        g.x = gelu_tanh(acc3.x); g.y = gelu_tanh(acc3.y); g.z = gelu_tanh(acc3.z); g.w = gelu_tanh(acc3.w);
        *(float4*)&zs[(r0 + 3) * ZSTR + j0] = g;
    }
    __syncthreads();

    // ---- phase 3: alpha[r][h] = z[r,:] . wkq[h] + bkq[h]
    {
        const int q   = tid >> 2;      // 0..63 -> (r,h)
        const int r   = q >> 1;
        const int h   = q & 1;
        const int seg = tid & 3;
        float p = 0.f;
        for (int m = 0; m < 8; ++m) {
            int d = seg * 32 + m * 4;
            float4 z4 = *(const float4*)&zs[r * ZSTR + d];
            float4 w4 = *(const float4*)&wkqs[h * 128 + d];
            p += z4.x * w4.x + z4.y * w4.y + z4.z * w4.z + z4.w * w4.w;
        }
        p += __shfl_xor(p, 1);
        p += __shfl_xor(p, 2);
        if (seg == 0) alphas[r * 2 + h] = p + bkqs[h];
    }
    __syncthreads();

    // ---- phase 4: S[b][h][d] += sum_r alpha[r][h]*z[r][d];  A[b][h] += sum_r alpha
    {
        const int h = tid >> 7;
        const int d = tid & 127;
        float s = 0.f;
        for (int r = 0; r < 32; ++r) s += alphas[r * 2 + h] * zs[r * ZSTR + d];
        atomicAdd(&ws[WS_S + (b * 2 + h) * 128 + d], s);
        if (tid < 2) {
            float a = 0.f;
            for (int r = 0; r < 32; ++r) a += alphas[r * 2 + tid];
            atomicAdd(&ws[WS_A + b * 2 + tid], a);
        }
    }
}

// K2: pooled = (S @ Wv_slice + A*bv)/N ; out = pooled @ Wo + bo. 32 blocks x 128.
__global__ __launch_bounds__(128) void epilogue_kernel(
    const float* __restrict__ Wv, const float* __restrict__ bv,
    const float* __restrict__ Wo, const float* __restrict__ bo,
    const float* __restrict__ ws, float* __restrict__ out)
{
    __shared__ float sS[256];
    __shared__ float sA[2];
    __shared__ float pooled[128];
    const int b = blockIdx.x, i = threadIdx.x;
    sS[i]       = ws[WS_S + b * 256 + i];
    sS[128 + i] = ws[WS_S + b * 256 + 128 + i];
    if (i < 2) sA[i] = ws[WS_A + b * 2 + i];
    __syncthreads();
    const int h = i >> 6;
    float dot = 0.f;
    for (int d = 0; d < 128; ++d) dot += sS[h * 128 + d] * Wv[d * 128 + i];
    pooled[i] = (dot + sA[h] * bv[i]) * (1.0f / 4096.0f);
    __syncthreads();
    float o = bo[i];
    for (int d = 0; d < 128; ++d) o += pooled[d] * Wo[d * 128 + i];
    out[b * 128 + i] = o;
}

extern "C" void kernel_launch(void* const* d_in, const int* in_sizes, int n_in,
                              void* d_out, int out_size, void* d_ws, size_t ws_size,
                              hipStream_t stream) {
    const float* u     = (const float*)d_in[0];
    // d_in[1] = x : unused by the reference
    const float* W1    = (const float*)d_in[2];
    const float* b1    = (const float*)d_in[3];
    const float* W2    = (const float*)d_in[4];
    const float* b2    = (const float*)d_in[5];
    const float* embed = (const float*)d_in[6];
    const float* Wq    = (const float*)d_in[7];
    const float* bq    = (const float*)d_in[8];
    const float* Wk    = (const float*)d_in[9];
    const float* bk    = (const float*)d_in[10];
    const float* Wv    = (const float*)d_in[11];
    const float* bv    = (const float*)d_in[12];
    const float* Wo    = (const float*)d_in[13];
    const float* bo    = (const float*)d_in[14];
    float* ws  = (float*)d_ws;
    float* out = (float*)d_out;

    hipLaunchKernelGGL(precompute_kernel, dim3(1), dim3(256), 0, stream,
                       embed, Wq, bq, Wk, bk, ws);
    hipLaunchKernelGGL(mlp_pool_kernel, dim3(Bsz * (Nn / 32)), dim3(256), 0, stream,
                       u, W1, b1, W2, b2, ws);
    hipLaunchKernelGGL(epilogue_kernel, dim3(Bsz), dim3(128), 0, stream,
                       Wv, bv, Wo, bo, ws, out);
}

// Round 2
// 180.748 us; speedup vs baseline: 1.3096x; 1.3096x over previous
//
#include <hip/hip_runtime.h>
#include <math.h>

// Problem constants
#define Bsz 32
#define Nn  4096
#define DU  64
#define Dm  128

// workspace layout (float offsets)
#define WS_WKQ 0      // [2][128]  Wk-slice @ q per head (summed over full z-dim)
#define WS_BKQ 256    // [2]       bk-slice . q
#define WS_A   288    // [32][2]   sum of alpha
#define WS_S   384    // [32][2][128] sum alpha*z
#define WS_WP  8576   // packed bf16 MFMA B-fragments: 48 frags * 64 lanes * 8 ushort = 49152 B
// total ws: 8576 + 12288 floats = 83.5 KB

#define H1STR 136     // shorts per h1 LDS row (128 + 8 pad) = 272 B, 16B-aligned

typedef short frag_ab __attribute__((ext_vector_type(8)));
typedef float frag_cd __attribute__((ext_vector_type(4)));

__device__ __forceinline__ unsigned short f2bf(float x) {
    union { float f; unsigned int u; } c; c.f = x;
    unsigned int r = c.u + 0x7fffu + ((c.u >> 16) & 1u);   // round-to-nearest-even
    return (unsigned short)(r >> 16);
}

__device__ __forceinline__ float gelu_tanh(float x) {
    const float c0 = 0.7978845608028654f;
    const float c1 = 0.044715f;
    float y = c0 * (x + c1 * x * x * x);
    float t = __expf(-2.0f * fabsf(y));      // in (0,1], no overflow
    float th = (1.0f - t) / (1.0f + t);      // |tanh(y)|
    th = copysignf(th, y);
    return 0.5f * x * (1.0f + th);
}

// K0: pack W1/W2 into MFMA B-frag order (bf16), compute wkq/bkq, zero S/A.
__global__ __launch_bounds__(256) void precompute_kernel(
    const float* __restrict__ embed, const float* __restrict__ Wq,
    const float* __restrict__ bq, const float* __restrict__ Wk,
    const float* __restrict__ bk, const float* __restrict__ W1,
    const float* __restrict__ W2, float* __restrict__ ws)
{
    __shared__ float qv[128];
    const int tid = threadIdx.x;

    for (int idx = tid; idx < 64;   idx += 256) ws[WS_A + idx] = 0.f;
    for (int idx = tid; idx < 8192; idx += 256) ws[WS_S + idx] = 0.f;

    // pack weights: frag f (0..15 -> W1 ks=f>>3,nt=f&7; 16..47 -> W2), lane L.
    // B-frag layout: lane L (quad=L>>4, n=L&15) holds B[ks*32+quad*8+j][nt*16+n], j=0..7
    {
        uint4* wp = (uint4*)(ws + WS_WP);
        for (int e = tid; e < 3072; e += 256) {
            const int f = e >> 6, L = e & 63;
            const int quad = L >> 4, n = L & 15;
            const float* src;
            int ks, nt;
            if (f < 16) { src = W1; ks = f >> 3;        nt = f & 7; }
            else        { src = W2; ks = (f - 16) >> 3; nt = (f - 16) & 7; }
            const int kb = ks * 32 + quad * 8;
            const int c  = nt * 16 + n;
            unsigned int p[4];
            #pragma unroll
            for (int jj = 0; jj < 4; ++jj) {
                unsigned int lo = f2bf(src[(kb + 2 * jj)     * Dm + c]);
                unsigned int hi = f2bf(src[(kb + 2 * jj + 1) * Dm + c]);
                p[jj] = lo | (hi << 16);
            }
            wp[e] = make_uint4(p[0], p[1], p[2], p[3]);
        }
    }

    if (tid < 128) {
        float s = bq[tid];
        for (int j = 0; j < 128; ++j) s += embed[j] * Wq[j * 128 + tid];
        qv[tid] = s;
    }
    __syncthreads();
    if (tid < 128) {
        float s0 = 0.f, s1 = 0.f;
        for (int dh = 0; dh < 64; ++dh) {
            s0 += Wk[tid * 128 + dh]      * qv[dh];
            s1 += Wk[tid * 128 + 64 + dh] * qv[64 + dh];
        }
        ws[WS_WKQ + tid]       = s0;
        ws[WS_WKQ + 128 + tid] = s1;
    }
    if (tid < 2) {
        float s = 0.f;
        for (int dh = 0; dh < 64; ++dh) s += bk[tid * 64 + dh] * qv[tid * 64 + dh];
        ws[WS_BKQ + tid] = s;
    }
}

// K1: bf16-MFMA fused MLP + alpha + S/A pooling.
// 512 blocks x 256 thr; block = 256 rows (4 iters x 4 waves x 16 rows).
__global__ __launch_bounds__(256, 2) void mlp_pool_kernel(
    const float* __restrict__ u,  const float* __restrict__ b1,
    const float* __restrict__ b2, float* __restrict__ ws)
{
    __shared__ short lds_w[48 * 512];        // 48 B-frags x 64 lanes x 8 bf16 = 48 KB
    __shared__ short lds_h1[4 * 16 * H1STR]; // per-wave 16 x 136 bf16

    const int tid  = threadIdx.x;
    const int wave = tid >> 6;
    const int lane = tid & 63;
    const int quad = lane >> 4;
    const int n15  = lane & 15;

    // stage packed weights global -> LDS (once per block)
    {
        const float4* src = (const float4*)(ws + WS_WP);
        float4* dst = (float4*)lds_w;
        for (int i = tid; i < 3072; i += 256) dst[i] = src[i];
    }

    // per-lane uniform preloads (L2-hot)
    float b1c[8], b2c[8], wkq0[8], wkq1[8];
    #pragma unroll
    for (int nt = 0; nt < 8; ++nt) {
        const int c = nt * 16 + n15;
        b1c[nt]  = b1[c];
        b2c[nt]  = b2[c];
        wkq0[nt] = ws[WS_WKQ + c];
        wkq1[nt] = ws[WS_WKQ + 128 + c];
    }
    const float bkq0 = ws[WS_BKQ];
    const float bkq1 = ws[WS_BKQ + 1];
    __syncthreads();

    const int block_row = blockIdx.x << 8;       // 256 rows per block
    const int b = blockIdx.x >> 4;               // 16 blocks per batch
    short* h1w = lds_h1 + wave * 16 * H1STR;

    float s0p[8], s1p[8];
    #pragma unroll
    for (int nt = 0; nt < 8; ++nt) { s0p[nt] = 0.f; s1p[nt] = 0.f; }
    float aA0 = 0.f, aA1 = 0.f;

    // prefetch u for iteration 0: lane reads row (m=n15), k in [quad*8, +8) and [32+quad*8, +8)
    const float* up = u + (size_t)(block_row + wave * 16 + n15) * DU + quad * 8;
    float4 f0 = *(const float4*)(up);
    float4 f1 = *(const float4*)(up + 4);
    float4 f2 = *(const float4*)(up + 32);
    float4 f3 = *(const float4*)(up + 36);

    for (int it = 0; it < 4; ++it) {
        // A-frags for layer 1 (bf16): a0 = k 0..31 slice, a1 = k 32..63 slice
        frag_ab a0, a1;
        a0[0] = (short)f2bf(f0.x); a0[1] = (short)f2bf(f0.y);
        a0[2] = (short)f2bf(f0.z); a0[3] = (short)f2bf(f0.w);
        a0[4] = (short)f2bf(f1.x); a0[5] = (short)f2bf(f1.y);
        a0[6] = (short)f2bf(f1.z); a0[7] = (short)f2bf(f1.w);
        a1[0] = (short)f2bf(f2.x); a1[1] = (short)f2bf(f2.y);
        a1[2] = (short)f2bf(f2.z); a1[3] = (short)f2bf(f2.w);
        a1[4] = (short)f2bf(f3.x); a1[5] = (short)f2bf(f3.y);
        a1[6] = (short)f2bf(f3.z); a1[7] = (short)f2bf(f3.w);

        // prefetch next iteration's u (overlaps with MFMA below)
        if (it < 3) {
            const float* upn = u + (size_t)(block_row + (it + 1) * 64 + wave * 16 + n15) * DU + quad * 8;
            f0 = *(const float4*)(upn);
            f1 = *(const float4*)(upn + 4);
            f2 = *(const float4*)(upn + 32);
            f3 = *(const float4*)(upn + 36);
        }

        // ---- layer 1: h1 = gelu(u @ W1 + b1), M16 x N128 x K64
        frag_cd acc[8];
        #pragma unroll
        for (int nt = 0; nt < 8; ++nt) acc[nt] = (frag_cd){0.f, 0.f, 0.f, 0.f};
        #pragma unroll
        for (int nt = 0; nt < 8; ++nt) {
            frag_ab w0 = *(const frag_ab*)&lds_w[(0 * 8 + nt) * 512 + lane * 8];
            acc[nt] = __builtin_amdgcn_mfma_f32_16x16x32_bf16(a0, w0, acc[nt], 0, 0, 0);
            frag_ab w1 = *(const frag_ab*)&lds_w[(1 * 8 + nt) * 512 + lane * 8];
            acc[nt] = __builtin_amdgcn_mfma_f32_16x16x32_bf16(a1, w1, acc[nt], 0, 0, 0);
        }

        // bias + gelu (fp32) -> h1 to wave-private LDS as bf16, row-major [m][H1STR]
        // D layout: row = quad*4+reg, col = nt*16+n15
        #pragma unroll
        for (int nt = 0; nt < 8; ++nt) {
            #pragma unroll
            for (int r = 0; r < 4; ++r) {
                float g = gelu_tanh(acc[nt][r] + b1c[nt]);
                h1w[(quad * 4 + r) * H1STR + nt * 16 + n15] = (short)f2bf(g);
            }
        }
        // no barrier: h1 region is wave-private; DS ops execute in order per wave

        // ---- layer 2: z = gelu(h1 @ W2 + b2), M16 x N128 x K128
        frag_cd acc2[8];
        #pragma unroll
        for (int nt = 0; nt < 8; ++nt) acc2[nt] = (frag_cd){0.f, 0.f, 0.f, 0.f};
        #pragma unroll
        for (int ks = 0; ks < 4; ++ks) {
            frag_ab a2 = *(const frag_ab*)&h1w[n15 * H1STR + ks * 32 + quad * 8];
            #pragma unroll
            for (int nt = 0; nt < 8; ++nt) {
                frag_ab w2f = *(const frag_ab*)&lds_w[(16 + ks * 8 + nt) * 512 + lane * 8];
                acc2[nt] = __builtin_amdgcn_mfma_f32_16x16x32_bf16(a2, w2f, acc2[nt], 0, 0, 0);
            }
        }

        // bias + gelu -> z stays fp32 in registers (overwrite acc2)
        #pragma unroll
        for (int nt = 0; nt < 8; ++nt) {
            #pragma unroll
            for (int r = 0; r < 4; ++r)
                acc2[nt][r] = gelu_tanh(acc2[nt][r] + b2c[nt]);
        }

        // ---- alpha[r][h] = sum_d z[r][d] * wkq[h][d] + bkq[h]
        float p0[4], p1[4];
        #pragma unroll
        for (int r = 0; r < 4; ++r) {
            float q0 = 0.f, q1 = 0.f;
            #pragma unroll
            for (int nt = 0; nt < 8; ++nt) {
                q0 += acc2[nt][r] * wkq0[nt];
                q1 += acc2[nt][r] * wkq1[nt];
            }
            p0[r] = q0; p1[r] = q1;
        }
        #pragma unroll
        for (int r = 0; r < 4; ++r) {
            #pragma unroll
            for (int d = 1; d < 16; d <<= 1) {
                p0[r] += __shfl_xor(p0[r], d);
                p1[r] += __shfl_xor(p1[r], d);
            }
            p0[r] += bkq0;
            p1[r] += bkq1;
        }

        // ---- accumulate S (both heads, all 128 dims) and A
        #pragma unroll
        for (int nt = 0; nt < 8; ++nt) {
            #pragma unroll
            for (int r = 0; r < 4; ++r) {
                s0p[nt] += p0[r] * acc2[nt][r];
                s1p[nt] += p1[r] * acc2[nt][r];
            }
        }
        #pragma unroll
        for (int r = 0; r < 4; ++r) { aA0 += p0[r]; aA1 += p1[r]; }
    }

    // cross-quad reduce (quads hold disjoint row groups), then one atomic batch
    #pragma unroll
    for (int nt = 0; nt < 8; ++nt) {
        s0p[nt] += __shfl_xor(s0p[nt], 16); s0p[nt] += __shfl_xor(s0p[nt], 32);
        s1p[nt] += __shfl_xor(s1p[nt], 16); s1p[nt] += __shfl_xor(s1p[nt], 32);
    }
    aA0 += __shfl_xor(aA0, 16); aA0 += __shfl_xor(aA0, 32);
    aA1 += __shfl_xor(aA1, 16); aA1 += __shfl_xor(aA1, 32);

    if (quad == 0) {
        #pragma unroll
        for (int nt = 0; nt < 8; ++nt) {
            const int c = nt * 16 + n15;
            atomicAdd(&ws[WS_S + (b * 2 + 0) * 128 + c], s0p[nt]);
            atomicAdd(&ws[WS_S + (b * 2 + 1) * 128 + c], s1p[nt]);
        }
    }
    if (lane == 0) {
        atomicAdd(&ws[WS_A + b * 2 + 0], aA0);
        atomicAdd(&ws[WS_A + b * 2 + 1], aA1);
    }
}

// K2: pooled = (S @ Wv_slice + A*bv)/N ; out = pooled @ Wo + bo. 32 blocks x 128.
__global__ __launch_bounds__(128) void epilogue_kernel(
    const float* __restrict__ Wv, const float* __restrict__ bv,
    const float* __restrict__ Wo, const float* __restrict__ bo,
    const float* __restrict__ ws, float* __restrict__ out)
{
    __shared__ float sS[256];
    __shared__ float sA[2];
    __shared__ float pooled[128];
    const int b = blockIdx.x, i = threadIdx.x;
    sS[i]       = ws[WS_S + b * 256 + i];
    sS[128 + i] = ws[WS_S + b * 256 + 128 + i];
    if (i < 2) sA[i] = ws[WS_A + b * 2 + i];
    __syncthreads();
    const int h = i >> 6;
    float dot = 0.f;
    for (int d = 0; d < 128; ++d) dot += sS[h * 128 + d] * Wv[d * 128 + i];
    pooled[i] = (dot + sA[h] * bv[i]) * (1.0f / 4096.0f);
    __syncthreads();
    float o = bo[i];
    for (int d = 0; d < 128; ++d) o += pooled[d] * Wo[d * 128 + i];
    out[b * 128 + i] = o;
}

extern "C" void kernel_launch(void* const* d_in, const int* in_sizes, int n_in,
                              void* d_out, int out_size, void* d_ws, size_t ws_size,
                              hipStream_t stream) {
    const float* u     = (const float*)d_in[0];
    // d_in[1] = x : unused by the reference
    const float* W1    = (const float*)d_in[2];
    const float* b1    = (const float*)d_in[3];
    const float* W2    = (const float*)d_in[4];
    const float* b2    = (const float*)d_in[5];
    const float* embed = (const float*)d_in[6];
    const float* Wq    = (const float*)d_in[7];
    const float* bq    = (const float*)d_in[8];
    const float* Wk    = (const float*)d_in[9];
    const float* bk    = (const float*)d_in[10];
    const float* Wv    = (const float*)d_in[11];
    const float* bv    = (const float*)d_in[12];
    const float* Wo    = (const float*)d_in[13];
    const float* bo    = (const float*)d_in[14];
    float* ws  = (float*)d_ws;
    float* out = (float*)d_out;

    hipLaunchKernelGGL(precompute_kernel, dim3(1), dim3(256), 0, stream,
                       embed, Wq, bq, Wk, bk, W1, W2, ws);
    hipLaunchKernelGGL(mlp_pool_kernel, dim3(512), dim3(256), 0, stream,
                       u, b1, b2, ws);
    hipLaunchKernelGGL(epilogue_kernel, dim3(Bsz), dim3(128), 0, stream,
                       Wv, bv, Wo, bo, ws, out);
}

// Round 3
// 172.094 us; speedup vs baseline: 1.3755x; 1.0503x over previous
//
#include <hip/hip_runtime.h>
#include <math.h>

// Problem constants
#define Bsz 32
#define Nn  4096
#define DU  64
#define Dm  128

// workspace layout (float offsets)
#define WS_WKQ 0      // [2][128]  Wk-slice @ q per head
#define WS_BKQ 256    // [2]       bk-slice . q
#define WS_A   288    // [32][2]   sum of alpha
#define WS_S   384    // [32][2][128] sum alpha*z
#define WS_WP  8576   // packed bf16 MFMA B-fragments: 48 frags * 64 lanes * 8 ushort

#define H1STR 136     // shorts per h1 LDS row (128 + 8 pad), 16B-aligned

typedef short frag_ab __attribute__((ext_vector_type(8)));
typedef float frag_cd __attribute__((ext_vector_type(4)));

__device__ __forceinline__ unsigned short f2bf(float x) {
    union { float f; unsigned int u; } c; c.f = x;
    unsigned int r = c.u + 0x7fffu + ((c.u >> 16) & 1u);   // RNE
    return (unsigned short)(r >> 16);
}

__device__ __forceinline__ float gelu_tanh(float x) {
    const float c0 = 0.7978845608028654f;
    const float c1 = 0.044715f;
    float y = c0 * (x + c1 * x * x * x);
    float t = __expf(-2.0f * fabsf(y));
    float th = (1.0f - t) / (1.0f + t);
    th = copysignf(th, y);
    return 0.5f * x * (1.0f + th);
}

// K0: 14 blocks. 0..11 pack W1/W2 into MFMA B-frag bf16 streams; 12 computes
// qv/wkq/bkq; 13 zeroes S/A accumulators.
__global__ __launch_bounds__(256) void precompute_kernel(
    const float* __restrict__ embed, const float* __restrict__ Wq,
    const float* __restrict__ bq, const float* __restrict__ Wk,
    const float* __restrict__ bk, const float* __restrict__ W1,
    const float* __restrict__ W2, float* __restrict__ ws)
{
    __shared__ float qv[128];
    const int tid = threadIdx.x;
    const int bid = blockIdx.x;

    if (bid < 12) {
        // B-frag layout: frag f, lane L (quad=L>>4, n=L&15) holds
        // B[ks*32 + quad*8 + j][nt*16 + n], j=0..7
        const int e = bid * 256 + tid;     // 0..3071
        const int f = e >> 6, L = e & 63;
        const int quad = L >> 4, n = L & 15;
        const float* src;
        int ks, nt;
        if (f < 16) { src = W1; ks = f >> 3;        nt = f & 7; }
        else        { src = W2; ks = (f - 16) >> 3; nt = (f - 16) & 7; }
        const int kb = ks * 32 + quad * 8;
        const int c  = nt * 16 + n;
        unsigned int p[4];
        #pragma unroll
        for (int jj = 0; jj < 4; ++jj) {
            unsigned int lo = f2bf(src[(kb + 2 * jj)     * Dm + c]);
            unsigned int hi = f2bf(src[(kb + 2 * jj + 1) * Dm + c]);
            p[jj] = lo | (hi << 16);
        }
        ((uint4*)(ws + WS_WP))[e] = make_uint4(p[0], p[1], p[2], p[3]);
    } else if (bid == 12) {
        if (tid < 128) {
            float s = bq[tid];
            #pragma unroll 8
            for (int j = 0; j < 128; ++j) s += embed[j] * Wq[j * 128 + tid];
            qv[tid] = s;
        }
        __syncthreads();
        if (tid < 128) {
            float s0 = 0.f, s1 = 0.f;
            #pragma unroll 8
            for (int dh = 0; dh < 64; ++dh) {
                s0 += Wk[tid * 128 + dh]      * qv[dh];
                s1 += Wk[tid * 128 + 64 + dh] * qv[64 + dh];
            }
            ws[WS_WKQ + tid]       = s0;
            ws[WS_WKQ + 128 + tid] = s1;
        }
        if (tid < 2) {
            float s = 0.f;
            for (int dh = 0; dh < 64; ++dh) s += bk[tid * 64 + dh] * qv[tid * 64 + dh];
            ws[WS_BKQ + tid] = s;
        }
    } else {
        for (int idx = tid; idx < 64;   idx += 256) ws[WS_A + idx] = 0.f;
        for (int idx = tid; idx < 8192; idx += 256) ws[WS_S + idx] = 0.f;
    }
}

// K1: bf16-MFMA fused MLP + alpha + S/A pooling.
// 512 blocks x 256 thr; block = 256 rows (4 iters x 4 waves x 16 rows).
__global__ __launch_bounds__(256, 2) void mlp_pool_kernel(
    const float* __restrict__ u,  const float* __restrict__ b1,
    const float* __restrict__ b2, float* __restrict__ ws)
{
    __shared__ short lds_w[48 * 512];        // 48 KB weight fragments
    __shared__ short lds_h1[4 * 16 * H1STR]; // per-wave 16 x 136 bf16

    const int tid  = threadIdx.x;
    const int wave = tid >> 6;
    const int lane = tid & 63;
    const int quad = lane >> 4;
    const int n15  = lane & 15;

    // stage packed weights global(L2) -> LDS, once per block
    {
        const float4* src = (const float4*)(ws + WS_WP);
        float4* dst = (float4*)lds_w;
        #pragma unroll
        for (int i = 0; i < 12; ++i) dst[tid + 256 * i] = src[tid + 256 * i];
    }

    // persistent per-lane constants (~40 VGPRs)
    float b1c[8], b2c[8], wkq0[8], wkq1[8];
    #pragma unroll
    for (int nt = 0; nt < 8; ++nt) {
        const int c = nt * 16 + n15;
        b1c[nt]  = b1[c];
        b2c[nt]  = b2[c];
        wkq0[nt] = ws[WS_WKQ + c];
        wkq1[nt] = ws[WS_WKQ + 128 + c];
    }
    const float bkq0 = ws[WS_BKQ];
    const float bkq1 = ws[WS_BKQ + 1];
    __syncthreads();

    const int block_row = blockIdx.x << 8;   // 256 rows per block
    const int b = blockIdx.x >> 4;           // 16 blocks per batch
    short* h1w = lds_h1 + wave * 16 * H1STR;

    float s0p[8], s1p[8];
    #pragma unroll
    for (int nt = 0; nt < 8; ++nt) { s0p[nt] = 0.f; s1p[nt] = 0.f; }
    float aA0 = 0.f, aA1 = 0.f;

    #pragma unroll 1            // do NOT unroll: unrolling caused VGPR spills (R2: 41MB scratch writes)
    for (int it = 0; it < 4; ++it) {
        // load 16 rows of u: lane (quad,n15) reads row n15(+wave*16), k=quad*8..+8 and +32
        const float* up = u + (size_t)(block_row + it * 64 + wave * 16 + n15) * DU + quad * 8;
        float4 f0 = *(const float4*)(up);
        float4 f1 = *(const float4*)(up + 4);
        float4 f2 = *(const float4*)(up + 32);
        float4 f3 = *(const float4*)(up + 36);

        frag_ab a0, a1;
        a0[0] = (short)f2bf(f0.x); a0[1] = (short)f2bf(f0.y);
        a0[2] = (short)f2bf(f0.z); a0[3] = (short)f2bf(f0.w);
        a0[4] = (short)f2bf(f1.x); a0[5] = (short)f2bf(f1.y);
        a0[6] = (short)f2bf(f1.z); a0[7] = (short)f2bf(f1.w);
        a1[0] = (short)f2bf(f2.x); a1[1] = (short)f2bf(f2.y);
        a1[2] = (short)f2bf(f2.z); a1[3] = (short)f2bf(f2.w);
        a1[4] = (short)f2bf(f3.x); a1[5] = (short)f2bf(f3.y);
        a1[6] = (short)f2bf(f3.z); a1[7] = (short)f2bf(f3.w);

        // ---- layer 1: h1 = gelu(u @ W1 + b1), M16 N128 K64
        frag_cd acc[8];
        #pragma unroll
        for (int nt = 0; nt < 8; ++nt) acc[nt] = (frag_cd){0.f, 0.f, 0.f, 0.f};
        #pragma unroll
        for (int nt = 0; nt < 8; ++nt) {
            frag_ab w0 = *(const frag_ab*)&lds_w[(nt)     * 512 + lane * 8];
            acc[nt] = __builtin_amdgcn_mfma_f32_16x16x32_bf16(a0, w0, acc[nt], 0, 0, 0);
            frag_ab w1 = *(const frag_ab*)&lds_w[(8 + nt) * 512 + lane * 8];
            acc[nt] = __builtin_amdgcn_mfma_f32_16x16x32_bf16(a1, w1, acc[nt], 0, 0, 0);
        }

        // bias + gelu (fp32) -> h1 bf16 in wave-private LDS [m][H1STR]
        // D layout: row = quad*4+reg, col = nt*16+n15
        #pragma unroll
        for (int nt = 0; nt < 8; ++nt) {
            #pragma unroll
            for (int r = 0; r < 4; ++r) {
                float g = gelu_tanh(acc[nt][r] + b1c[nt]);
                h1w[(quad * 4 + r) * H1STR + nt * 16 + n15] = (short)f2bf(g);
            }
        }
        // no barrier: wave-private region, per-wave DS ordering

        // ---- layer 2: z = gelu(h1 @ W2 + b2), M16 N128 K128
        frag_cd acc2[8];
        #pragma unroll
        for (int nt = 0; nt < 8; ++nt) acc2[nt] = (frag_cd){0.f, 0.f, 0.f, 0.f};
        #pragma unroll
        for (int ks = 0; ks < 4; ++ks) {
            frag_ab a2 = *(const frag_ab*)&h1w[n15 * H1STR + ks * 32 + quad * 8];
            #pragma unroll
            for (int nt = 0; nt < 8; ++nt) {
                frag_ab w2f = *(const frag_ab*)&lds_w[(16 + ks * 8 + nt) * 512 + lane * 8];
                acc2[nt] = __builtin_amdgcn_mfma_f32_16x16x32_bf16(a2, w2f, acc2[nt], 0, 0, 0);
            }
        }

        // bias + gelu -> z fp32 in registers
        #pragma unroll
        for (int nt = 0; nt < 8; ++nt) {
            #pragma unroll
            for (int r = 0; r < 4; ++r)
                acc2[nt][r] = gelu_tanh(acc2[nt][r] + b2c[nt]);
        }

        // ---- alpha[r][h] = z[r,:] . wkq[h] + bkq[h] (reduce over n15 lanes)
        float p0[4], p1[4];
        #pragma unroll
        for (int r = 0; r < 4; ++r) {
            float q0 = 0.f, q1 = 0.f;
            #pragma unroll
            for (int nt = 0; nt < 8; ++nt) {
                q0 += acc2[nt][r] * wkq0[nt];
                q1 += acc2[nt][r] * wkq1[nt];
            }
            p0[r] = q0; p1[r] = q1;
        }
        #pragma unroll
        for (int r = 0; r < 4; ++r) {
            #pragma unroll
            for (int d = 1; d < 16; d <<= 1) {
                p0[r] += __shfl_xor(p0[r], d);
                p1[r] += __shfl_xor(p1[r], d);
            }
            p0[r] += bkq0;
            p1[r] += bkq1;
        }

        // ---- accumulate S and A
        #pragma unroll
        for (int nt = 0; nt < 8; ++nt) {
            #pragma unroll
            for (int r = 0; r < 4; ++r) {
                s0p[nt] += p0[r] * acc2[nt][r];
                s1p[nt] += p1[r] * acc2[nt][r];
            }
        }
        #pragma unroll
        for (int r = 0; r < 4; ++r) { aA0 += p0[r]; aA1 += p1[r]; }
    }

    // cross-quad reduce (quads hold disjoint rows), one atomic batch per wave
    #pragma unroll
    for (int nt = 0; nt < 8; ++nt) {
        s0p[nt] += __shfl_xor(s0p[nt], 16); s0p[nt] += __shfl_xor(s0p[nt], 32);
        s1p[nt] += __shfl_xor(s1p[nt], 16); s1p[nt] += __shfl_xor(s1p[nt], 32);
    }
    aA0 += __shfl_xor(aA0, 16); aA0 += __shfl_xor(aA0, 32);
    aA1 += __shfl_xor(aA1, 16); aA1 += __shfl_xor(aA1, 32);

    if (quad == 0) {
        #pragma unroll
        for (int nt = 0; nt < 8; ++nt) {
            const int c = nt * 16 + n15;
            atomicAdd(&ws[WS_S + (b * 2 + 0) * 128 + c], s0p[nt]);
            atomicAdd(&ws[WS_S + (b * 2 + 1) * 128 + c], s1p[nt]);
        }
    }
    if (lane == 0) {
        atomicAdd(&ws[WS_A + b * 2 + 0], aA0);
        atomicAdd(&ws[WS_A + b * 2 + 1], aA1);
    }
}

// K2: pooled = (S @ Wv_slice + A*bv)/N ; out = pooled @ Wo + bo.
// 32 blocks x 256 thr, split-K by 2 to halve serial dot chains.
__global__ __launch_bounds__(256) void epilogue_kernel(
    const float* __restrict__ Wv, const float* __restrict__ bv,
    const float* __restrict__ Wo, const float* __restrict__ bo,
    const float* __restrict__ ws, float* __restrict__ out)
{
    __shared__ float sS[256];
    __shared__ float sA[2];
    __shared__ float pooled[128];
    __shared__ float part[256];
    const int b = blockIdx.x, tid = threadIdx.x;
    const int i = tid & 127, hf = tid >> 7;

    sS[tid] = ws[WS_S + b * 256 + tid];
    if (tid < 2) sA[tid] = ws[WS_A + b * 2 + tid];
    __syncthreads();

    const int h = i >> 6;
    float dot = 0.f;
    #pragma unroll 8
    for (int d0 = 0; d0 < 64; ++d0) {
        const int d = hf * 64 + d0;
        dot += sS[h * 128 + d] * Wv[d * 128 + i];
    }
    part[tid] = dot;
    __syncthreads();
    if (tid < 128)
        pooled[i] = (part[i] + part[128 + i] + sA[h] * bv[i]) * (1.0f / 4096.0f);
    __syncthreads();

    float o = 0.f;
    #pragma unroll 8
    for (int d0 = 0; d0 < 64; ++d0) {
        const int d = hf * 64 + d0;
        o += pooled[d] * Wo[d * 128 + i];
    }
    part[tid] = o;
    __syncthreads();
    if (tid < 128)
        out[b * 128 + i] = bo[i] + part[i] + part[128 + i];
}

extern "C" void kernel_launch(void* const* d_in, const int* in_sizes, int n_in,
                              void* d_out, int out_size, void* d_ws, size_t ws_size,
                              hipStream_t stream) {
    const float* u     = (const float*)d_in[0];
    // d_in[1] = x : unused by the reference
    const float* W1    = (const float*)d_in[2];
    const float* b1    = (const float*)d_in[3];
    const float* W2    = (const float*)d_in[4];
    const float* b2    = (const float*)d_in[5];
    const float* embed = (const float*)d_in[6];
    const float* Wq    = (const float*)d_in[7];
    const float* bq    = (const float*)d_in[8];
    const float* Wk    = (const float*)d_in[9];
    const float* bk    = (const float*)d_in[10];
    const float* Wv    = (const float*)d_in[11];
    const float* bv    = (const float*)d_in[12];
    const float* Wo    = (const float*)d_in[13];
    const float* bo    = (const float*)d_in[14];
    float* ws  = (float*)d_ws;
    float* out = (float*)d_out;

    hipLaunchKernelGGL(precompute_kernel, dim3(14), dim3(256), 0, stream,
                       embed, Wq, bq, Wk, bk, W1, W2, ws);
    hipLaunchKernelGGL(mlp_pool_kernel, dim3(512), dim3(256), 0, stream,
                       u, b1, b2, ws);
    hipLaunchKernelGGL(epilogue_kernel, dim3(Bsz), dim3(256), 0, stream,
                       Wv, bv, Wo, bo, ws, out);
}